// Round 8
// baseline (8394.006 us; speedup 1.0000x reference)
//
#include <hip/hip_runtime.h>
#include <math.h>

#define BQ 32
#define TQ 512
#define DQ 768
#define KQ 256
#define HQ 512
#define G4 2048
#define BROW 768   // buf row: h[0:512) | A[512:768)
#define STP 772    // LDS state row stride (pad for banks)
#define NWG 512    // 16 groups x 32 WGs
#define NTHR 256
#define NBG 2      // batches per group
#define GW 32      // WGs per group

typedef float f32x4 __attribute__((ext_vector_type(4)));

// Device (agent) scope = sc1 on gfx950: coherent across XCDs.
__device__ __forceinline__ void st_dev(float* p, float v) {
  asm volatile("global_store_dword %0, %1, off sc1" :: "v"(p), "v"(v) : "memory");
}
__device__ __forceinline__ int ld_dev(const int* p) {
  int v;
  asm volatile("global_load_dword %0, %1, off sc1\ns_waitcnt vmcnt(0)"
               : "=v"(v) : "v"(p) : "memory");
  return v;
}
// one counter per group per phase, own 128B line; wave0 polls one address
__device__ __forceinline__ void wg_wait_ctr(const int* ctr, int target) {
  if (threadIdx.x < 64) {
    while (ld_dev(ctr) < target) __builtin_amdgcn_s_sleep(1);
  }
  __syncthreads();
}
__device__ __forceinline__ void wg_signal_ctr(int* ctr) {
  asm volatile("s_waitcnt vmcnt(0) lgkmcnt(0)" ::: "memory");
  __syncthreads();
  if (threadIdx.x == 0) atomicAdd(ctr, 1);
}
__device__ __forceinline__ float sigm(float x) { return 1.f / (1.f + __expf(-x)); }

// ---------------- P1: Gram matrix G[b][t][tau] = x_t . x_tau ----------------
__global__ void __launch_bounds__(256) gram_k(const float* __restrict__ X,
                                              float* __restrict__ Gm) {
  __shared__ __align__(16) float As[64 * 33];
  __shared__ __align__(16) float Bs[64 * 33];
  const int bid = blockIdx.x;
  const int b = blockIdx.y;
  int I = 0, base = 0;
  while (base + I + 1 <= bid) { base += I + 1; ++I; }
  const int J = bid - base;
  const int t0 = I * 64, u0 = J * 64;
  const float* Xb = X + (size_t)b * TQ * DQ;
  const int ty = threadIdx.x >> 4, tx = threadIdx.x & 15;
  const int sc = threadIdx.x & 31, sr = threadIdx.x >> 5;
  float acc[4][4];
#pragma unroll
  for (int i = 0; i < 4; ++i)
#pragma unroll
    for (int j = 0; j < 4; ++j) acc[i][j] = 0.f;
  for (int k0 = 0; k0 < DQ; k0 += 32) {
#pragma unroll
    for (int rr = 0; rr < 8; ++rr) {
      const int r = rr * 8 + sr;
      As[r * 33 + sc] = Xb[(size_t)(t0 + r) * DQ + k0 + sc];
      Bs[r * 33 + sc] = Xb[(size_t)(u0 + r) * DQ + k0 + sc];
    }
    __syncthreads();
#pragma unroll
    for (int k = 0; k < 32; ++k) {
      float av[4], bv[4];
#pragma unroll
      for (int i = 0; i < 4; ++i) av[i] = As[(ty * 4 + i) * 33 + k];
#pragma unroll
      for (int j = 0; j < 4; ++j) bv[j] = Bs[(tx * 4 + j) * 33 + k];
#pragma unroll
      for (int i = 0; i < 4; ++i)
#pragma unroll
        for (int j = 0; j < 4; ++j) acc[i][j] += av[i] * bv[j];
    }
    __syncthreads();
  }
  float* gb = Gm + (size_t)b * TQ * TQ;
#pragma unroll
  for (int i = 0; i < 4; ++i) {
    f32x4 o;
    o.x = acc[i][0]; o.y = acc[i][1]; o.z = acc[i][2]; o.w = acc[i][3];
    *(f32x4*)&gb[(size_t)(t0 + ty * 4 + i) * TQ + u0 + tx * 4] = o;
  }
}

// ---------------- P2: row softmax (tau < t) in place + S[b][t] ----------------
__global__ void __launch_bounds__(256) smax_k(float* __restrict__ Gm,
                                              float* __restrict__ Sv,
                                              const float* __restrict__ cgp,
                                              const float* __restrict__ cbp) {
  const int t = blockIdx.x + 1;   // 1..511
  const int b = blockIdx.y;
  const int tid = threadIdx.x;
  const int lane = tid & 63;
  const int wv = tid >> 6;
  __shared__ float row[TQ];
  __shared__ float r1[4], r2[4], r3[4];
  float* R = Gm + ((size_t)b * TQ + t) * TQ;
  const float cg = cgp[0], cb = cbp[0];
  for (int i = tid; i < t; i += 256) row[i] = R[i];
  __syncthreads();
  float m = -3e38f;
  for (int i = tid; i < t; i += 256) m = fmaxf(m, row[i]);
#pragma unroll
  for (int k = 1; k < 64; k <<= 1) m = fmaxf(m, __shfl_xor(m, k));
  if (lane == 0) r1[wv] = m;
  __syncthreads();
  m = fmaxf(fmaxf(r1[0], r1[1]), fmaxf(r1[2], r1[3]));
  float s = 0.f, sck = 0.f;
  for (int i = tid; i < t; i += 256) {
    const float r = row[i];
    const float e = __expf(r - m);
    const float ck = 1.f / (1.f + __expf(-(r * cg + cb)));
    row[i] = e; s += e; sck += e * ck;
  }
#pragma unroll
  for (int k = 1; k < 64; k <<= 1) { s += __shfl_xor(s, k); sck += __shfl_xor(sck, k); }
  if (lane == 0) { r2[wv] = s; r3[wv] = sck; }
  __syncthreads();
  s = r2[0] + r2[1] + r2[2] + r2[3];
  sck = r3[0] + r3[1] + r3[2] + r3[3];
  const float inv = 1.f / s;
  for (int i = tid; i < t; i += 256) R[i] = row[i] * inv;
  if (tid == 0) Sv[(size_t)b * TQ + t] = sck * inv;
}

// ---------------- K3: persistent recurrence, 16 groups x 32 WGs x 2 batches --
// Per-WG compute identical to the 64x4 layout (64 z-cols x 2 batches), but
// fan-in halves (32 adds/ctr, straggler max-of-32) and per-step staging burst
// halves (6KB/WG). Same split ctrH/ctrA skeleton as R5.
__global__ void __launch_bounds__(NTHR, 2) esbn_scan(
    const float* __restrict__ Wx, const float* __restrict__ Wh,
    const float* __restrict__ bl, const float* __restrict__ Wk,
    const float* __restrict__ bk, const float* __restrict__ Wg,
    const float* __restrict__ bgp, const float* __restrict__ Wmat,
    const float* __restrict__ Sv, float* buf, int* ctrs,
    float* __restrict__ out) {
  __shared__ __align__(16) float st[NBG * STP];      // [h | A] per local batch
  __shared__ __align__(16) float wrow[4 * TQ];       // per-wave softmax row copy
  __shared__ __align__(16) float Mk_s[16 * 520];     // [b*8+kl][tau] key mem
  __shared__ __align__(16) float wkey_s[8 * 520];
  __shared__ __align__(16) float wgv[HQ];
  __shared__ __align__(16) float svl[NBG * TQ];      // Sv rows for this group
  __shared__ __align__(16) float zred[4 * 16 * NBG * 4];
  __shared__ float c_s[NBG * 16];
  __shared__ float bl_s[64];
  __shared__ float bk_s[8];
  __shared__ float bg_s;

  const int tid = threadIdx.x;
  const int wg = blockIdx.x & 31;    // 0..31 within group
  const int grp = blockIdx.x >> 5;   // 0..15
  const int b0 = grp * NBG;
  const int dc = tid >> 4;   // d-chunk 0..15
  const int cg = tid & 15;   // col group (4 cols)

  int colg[4];
#pragma unroll
  for (int j = 0; j < 4; ++j) {
    const int c = cg * 4 + j;                       // 0..63
    colg[j] = (c >> 4) * HQ + wg * 16 + (c & 15);   // gate*H + unit
  }
  f32x4 wh[32], wxr[16], wxl;
#pragma unroll
  for (int i = 0; i < 32; ++i) {
    const int d = (i << 4) + dc;
    wh[i].x = Wh[(size_t)d * G4 + colg[0]];
    wh[i].y = Wh[(size_t)d * G4 + colg[1]];
    wh[i].z = Wh[(size_t)d * G4 + colg[2]];
    wh[i].w = Wh[(size_t)d * G4 + colg[3]];
  }
#pragma unroll
  for (int i = 0; i < 16; ++i) {
    const int d = (i << 4) + dc;
    wxr[i].x = Wx[(size_t)d * G4 + colg[0]];
    wxr[i].y = Wx[(size_t)d * G4 + colg[1]];
    wxr[i].z = Wx[(size_t)d * G4 + colg[2]];
    wxr[i].w = Wx[(size_t)d * G4 + colg[3]];
  }
  wxl.x = Wx[(size_t)256 * G4 + colg[0]];
  wxl.y = Wx[(size_t)256 * G4 + colg[1]];
  wxl.z = Wx[(size_t)256 * G4 + colg[2]];
  wxl.w = Wx[(size_t)256 * G4 + colg[3]];

  for (int i = tid; i < NBG * STP; i += NTHR) st[i] = 0.f;
  for (int i = tid; i < 16 * 520; i += NTHR) Mk_s[i] = 0.f;
  for (int i = tid; i < 8 * 520; i += NTHR) {
    const int kl = i / 520, u = i - kl * 520;
    wkey_s[i] = (u < HQ) ? Wk[(size_t)u * KQ + wg * 8 + kl] : 0.f;
  }
  for (int i = tid; i < HQ; i += NTHR) wgv[i] = Wg[i];
  for (int i = tid; i < NBG * TQ; i += NTHR)
    svl[i] = Sv[(size_t)(b0 + (i >> 9)) * TQ + (i & 511)];
  if (tid < 64) bl_s[tid] = bl[(tid >> 4) * HQ + wg * 16 + (tid & 15)];
  if (tid < 8) bk_s[tid] = bk[wg * 8 + tid];
  if (tid == 0) bg_s = bgp[0];
  if (tid < NBG * 16) c_s[tid] = 0.f;
  __syncthreads();

  int* ctrH = ctrs + grp * 64;       // own 128B line
  int* ctrA = ctrs + grp * 64 + 32;  // own 128B line
  const int wv0 = tid >> 6;          // wave 0..3
  const int yb2 = tid >> 7;          // batch for wrow prefetch (waves 01->0, 23->1)
  const int lt = tid & 63;
  const int row = tid >> 4;          // A-block row 0..15 (b = row>>3, kl = row&7)
  const int ytc = tid & 15;

  for (int t = 0; t < TQ; ++t) {
    const int p = t & 1, pn = p ^ 1;
    // prefetch softmax row t into regs (flag-independent; consumed in A-block)
    float wv8[8];
    const bool rowv = (t >= 1) && (t < TQ - 1);
    if (rowv) {
      const float* wr = Wmat + ((size_t)(b0 + yb2) * TQ + t) * TQ + lt;
#pragma unroll
      for (int k = 0; k < 8; ++k) wv8[k] = wr[k << 6];
    }
    if (t > 0) {
      wg_wait_ctr(ctrH, GW * t);   // h_{t-1} published by all 32 WGs
      const float* base = buf + (size_t)(p * BQ + b0) * BROW;
      f32x4 v0;
      const int hb = tid >> 7, off = (tid & 127) << 2;   // 256 f4 chunks
      const float* q0 = base + hb * BROW + off;
      asm volatile("global_load_dwordx4 %0, %1, off sc1" : "=v"(v0) : "v"(q0));
      asm volatile("s_waitcnt vmcnt(0)" : "+v"(v0) : : "memory");
      *(f32x4*)&st[hb * STP + off] = v0;
    }
    __syncthreads();   // st h ready
    // h-part of z (producers' A-block hides under this GEMM)
    f32x4 acc[NBG];
#pragma unroll
    for (int b = 0; b < NBG; ++b) { acc[b].x = acc[b].y = acc[b].z = acc[b].w = 0.f; }
#pragma unroll
    for (int i = 0; i < 32; ++i) {
      const f32x4 w = wh[i];
      const int d = (i << 4) + dc;
#pragma unroll
      for (int b = 0; b < NBG; ++b) acc[b] += st[b * STP + d] * w;
    }
    // g_{t-1}[0..1] per-wave: 16-lane sub-group per batch (duplicated x2)
    float gv[NBG];
    {
      const int sb = (lt >> 4) & 1, sl = lt & 15;
      const float* hb = &st[sb * STP];
      float a = 0.f;
#pragma unroll
      for (int j = 0; j < 32; ++j) {
        const int u = sl + (j << 4);
        a += hb[u] * wgv[u];
      }
      a += __shfl_xor(a, 1);
      a += __shfl_xor(a, 2);
      a += __shfl_xor(a, 4);
      a += __shfl_xor(a, 8);
#pragma unroll
      for (int b = 0; b < NBG; ++b) gv[b] = sigm(__shfl(a, b << 4) + bg_s);
    }
    if (t > 0) {
      wg_wait_ctr(ctrA, GW * t);   // A_{t-1} (usually already satisfied)
      if (tid < 128) {             // 128 f4 chunks
        const float* base = buf + (size_t)(p * BQ + b0) * BROW;
        f32x4 v2;
        const int ab = tid >> 6, off2 = (tid & 63) << 2;
        const float* q2 = base + ab * BROW + 512 + off2;
        asm volatile("global_load_dwordx4 %0, %1, off sc1" : "=v"(v2) : "v"(q2));
        asm volatile("s_waitcnt vmcnt(0)" : "+v"(v2) : : "memory");
        *(f32x4*)&st[ab * STP + 512 + off2] = v2;
      }
    }
    __syncthreads();   // st A ready
    // key_r part: pk = A.Wx + S*Wx[256]; z += g*pk
    f32x4 pk[NBG];
#pragma unroll
    for (int b = 0; b < NBG; ++b) { pk[b].x = pk[b].y = pk[b].z = pk[b].w = 0.f; }
#pragma unroll
    for (int i = 0; i < 16; ++i) {
      const f32x4 w = wxr[i];
      const int d = 512 + (i << 4) + dc;
#pragma unroll
      for (int b = 0; b < NBG; ++b) pk[b] += st[b * STP + d] * w;
    }
    if (dc == 0 && t > 0) {
#pragma unroll
      for (int b = 0; b < NBG; ++b) pk[b] += svl[(b << 9) + t - 1] * wxl;
    }
#pragma unroll
    for (int b = 0; b < NBG; ++b) {
      const float g = gv[b];
      acc[b].x += g * pk[b].x; acc[b].y += g * pk[b].y;
      acc[b].z += g * pk[b].z; acc[b].w += g * pk[b].w;
    }
    // reduce over dc low bits (in-wave lanes 16,32)
#pragma unroll
    for (int m = 16; m <= 32; m <<= 1) {
#pragma unroll
      for (int b = 0; b < NBG; ++b) {
        acc[b].x += __shfl_xor(acc[b].x, m);
        acc[b].y += __shfl_xor(acc[b].y, m);
        acc[b].z += __shfl_xor(acc[b].z, m);
        acc[b].w += __shfl_xor(acc[b].w, m);
      }
    }
    if (lt < 16) {
#pragma unroll
      for (int b = 0; b < NBG; ++b)
        *(f32x4*)&zred[((wv0 * 16 + lt) * NBG + b) * 4] = acc[b];
    }
    __syncthreads();
    if (tid < 32) {   // LSTM pointwise: thread = (b,u), wave 0 only
      const int b = tid >> 4, u = tid & 15;
      float zg[4];
#pragma unroll
      for (int g = 0; g < 4; ++g) {
        const int cgi = g * 4 + (u >> 2), comp = u & 3;
        float z = bl_s[g * 16 + u];
#pragma unroll
        for (int w = 0; w < 4; ++w) z += zred[((w * 16 + cgi) * NBG + b) * 4 + comp];
        zg[g] = z;
      }
      const float gi = sigm(zg[0]);
      const float gf = sigm(zg[1]);
      const float go = sigm(zg[3]);
      const float cn = gf * c_s[tid] + gi * tanhf(zg[2]);
      const float hv = go * tanhf(cn);
      c_s[tid] = cn;
      if (t == TQ - 1) out[(size_t)(b0 + b) * HQ + wg * 16 + u] = hv;
      else st_dev(buf + (size_t)(pn * BQ + b0 + b) * BROW + wg * 16 + u, hv);
    }
    if (t == TQ - 1) break;
    // lean h publish: stores came only from wave 0 -> wave-0 drain + atomic
    if (tid < 64) {
      asm volatile("s_waitcnt vmcnt(0)" ::: "memory");
      if (tid == 0) atomicAdd(ctrH, 1);
    }
    // A-block (off the h critical path): A_t on old Mk, kw folded in at the end.
    // Each wave keeps a private copy of its batch's softmax row (same-wave LDS).
    if (t >= 1) {
      float* wrw = &wrow[wv0 * TQ];
#pragma unroll
      for (int k = 0; k < 8; ++k) wrw[lt + (k << 6)] = wv8[k];
      const int b = row >> 3, kl = row & 7;
      float kw = 0.f, accA = 0.f;
      const float* hrow = &st[b * STP];
      const float* wkr = &wkey_s[kl * 520];
      const float* mk = &Mk_s[row * 520];
#pragma unroll
      for (int j = 0; j < 32; ++j) {
        const int u = ytc + (j << 4);
        kw += hrow[u] * wkr[u];
        accA += wrw[u] * mk[u];   // Mk[t-1] slot still zero: term added below
      }
#pragma unroll
      for (int m = 1; m <= 8; m <<= 1) {
        kw += __shfl_xor(kw, m);
        accA += __shfl_xor(accA, m);
      }
      kw += bk_s[kl];
      accA += wrw[t - 1] * kw;    // the tau = t-1 contribution
      if (ytc == 0) {
        st_dev(buf + (size_t)(pn * BQ + b0 + b) * BROW + 512 + wg * 8 + kl, accA);
        Mk_s[row * 520 + (t - 1)] = kw;
      }
    }
    wg_signal_ctr(ctrA);
  }
}

extern "C" void kernel_launch(void* const* d_in, const int* in_sizes, int n_in,
                              void* d_out, int out_size, void* d_ws, size_t ws_size,
                              hipStream_t stream) {
  (void)in_sizes; (void)n_in; (void)out_size; (void)ws_size;
  const float* X  = (const float*)d_in[0];
  const float* Wx = (const float*)d_in[1];
  const float* Wh = (const float*)d_in[2];
  const float* bl = (const float*)d_in[3];
  const float* Wk = (const float*)d_in[4];
  const float* bk = (const float*)d_in[5];
  const float* Wg = (const float*)d_in[6];
  const float* bg = (const float*)d_in[7];
  const float* cg = (const float*)d_in[8];
  const float* cb = (const float*)d_in[9];
  float* out = (float*)d_out;
  float* ws = (float*)d_ws;

  float* Gm = ws;                              // 32*512*512 = 8,388,608 f
  float* Sv = ws + (size_t)8388608;            // 32*512 = 16,384 f
  float* buf = ws + (size_t)8404992;           // 2*32*768 = 49,152 f
  int* ctrs = (int*)(ws + (size_t)8454144);    // 16 x 64 ints (2 x 128B/group)

  // zero Sv | state double-buffer | counters (one contiguous region)
  hipMemsetAsync(Sv, 0, (size_t)(16384 + 49152 + 1024) * 4, stream);
  gram_k<<<dim3(36, BQ), dim3(256), 0, stream>>>(X, Gm);
  smax_k<<<dim3(TQ - 1, BQ), dim3(256), 0, stream>>>(Gm, Sv, cg, cb);

  void* args[] = {(void*)&Wx, (void*)&Wh, (void*)&bl, (void*)&Wk, (void*)&bk,
                  (void*)&Wg, (void*)&bg, (void*)&Gm, (void*)&Sv,
                  (void*)&buf, (void*)&ctrs, (void*)&out};
  hipError_t e = hipLaunchCooperativeKernel((const void*)esbn_scan, dim3(NWG),
                                            dim3(NTHR), args, 0, stream);
  if (e != hipSuccess) {
    esbn_scan<<<dim3(NWG), dim3(NTHR), 0, stream>>>(Wx, Wh, bl, Wk, bk, Wg, bg,
                                                    Gm, Sv, buf, ctrs, out);
  }
}

// Round 9
// 4172.908 us; speedup vs baseline: 2.0115x; 2.0115x over previous
//
#include <hip/hip_runtime.h>
#include <math.h>

#define BQ 32
#define TQ 512
#define DQ 768
#define KQ 256
#define HQ 512
#define G4 2048
#define BROW 768   // buf row: h[0:512) | A[512:768)
#define STP 772    // LDS state row stride (pad for banks)
#define NWG 256    // 8 groups x 32 WGs
#define NTHR 512
#define NBG 4      // batches per group
#define GW 32      // WGs per group

typedef float f32x4 __attribute__((ext_vector_type(4)));

// Device (agent) scope = sc1 on gfx950: coherent across XCDs.
__device__ __forceinline__ void st_dev(float* p, float v) {
  asm volatile("global_store_dword %0, %1, off sc1" :: "v"(p), "v"(v) : "memory");
}
__device__ __forceinline__ int ld_dev(const int* p) {
  int v;
  asm volatile("global_load_dword %0, %1, off sc1\ns_waitcnt vmcnt(0)"
               : "=v"(v) : "v"(p) : "memory");
  return v;
}
// one counter per group per phase, own 128B line; wave0 polls one address
__device__ __forceinline__ void wg_wait_ctr(const int* ctr, int target) {
  if (threadIdx.x < 64) {
    while (ld_dev(ctr) < target) __builtin_amdgcn_s_sleep(1);
  }
  __syncthreads();
}
__device__ __forceinline__ void wg_signal_ctr(int* ctr) {
  asm volatile("s_waitcnt vmcnt(0) lgkmcnt(0)" ::: "memory");
  __syncthreads();
  if (threadIdx.x == 0) atomicAdd(ctr, 1);
}
__device__ __forceinline__ float sigm(float x) { return 1.f / (1.f + __expf(-x)); }

// ---------------- P1: Gram matrix G[b][t][tau] = x_t . x_tau ----------------
__global__ void __launch_bounds__(256) gram_k(const float* __restrict__ X,
                                              float* __restrict__ Gm) {
  __shared__ __align__(16) float As[64 * 33];
  __shared__ __align__(16) float Bs[64 * 33];
  const int bid = blockIdx.x;
  const int b = blockIdx.y;
  int I = 0, base = 0;
  while (base + I + 1 <= bid) { base += I + 1; ++I; }
  const int J = bid - base;
  const int t0 = I * 64, u0 = J * 64;
  const float* Xb = X + (size_t)b * TQ * DQ;
  const int ty = threadIdx.x >> 4, tx = threadIdx.x & 15;
  const int sc = threadIdx.x & 31, sr = threadIdx.x >> 5;
  float acc[4][4];
#pragma unroll
  for (int i = 0; i < 4; ++i)
#pragma unroll
    for (int j = 0; j < 4; ++j) acc[i][j] = 0.f;
  for (int k0 = 0; k0 < DQ; k0 += 32) {
#pragma unroll
    for (int rr = 0; rr < 8; ++rr) {
      const int r = rr * 8 + sr;
      As[r * 33 + sc] = Xb[(size_t)(t0 + r) * DQ + k0 + sc];
      Bs[r * 33 + sc] = Xb[(size_t)(u0 + r) * DQ + k0 + sc];
    }
    __syncthreads();
#pragma unroll
    for (int k = 0; k < 32; ++k) {
      float av[4], bv[4];
#pragma unroll
      for (int i = 0; i < 4; ++i) av[i] = As[(ty * 4 + i) * 33 + k];
#pragma unroll
      for (int j = 0; j < 4; ++j) bv[j] = Bs[(tx * 4 + j) * 33 + k];
#pragma unroll
      for (int i = 0; i < 4; ++i)
#pragma unroll
        for (int j = 0; j < 4; ++j) acc[i][j] += av[i] * bv[j];
    }
    __syncthreads();
  }
  float* gb = Gm + (size_t)b * TQ * TQ;
#pragma unroll
  for (int i = 0; i < 4; ++i) {
    f32x4 o;
    o.x = acc[i][0]; o.y = acc[i][1]; o.z = acc[i][2]; o.w = acc[i][3];
    *(f32x4*)&gb[(size_t)(t0 + ty * 4 + i) * TQ + u0 + tx * 4] = o;
  }
}

// ---------------- P2: row softmax (tau < t) in place + S[b][t] ----------------
__global__ void __launch_bounds__(256) smax_k(float* __restrict__ Gm,
                                              float* __restrict__ Sv,
                                              const float* __restrict__ cgp,
                                              const float* __restrict__ cbp) {
  const int t = blockIdx.x + 1;   // 1..511
  const int b = blockIdx.y;
  const int tid = threadIdx.x;
  const int lane = tid & 63;
  const int wv = tid >> 6;
  __shared__ float row[TQ];
  __shared__ float r1[4], r2[4], r3[4];
  float* R = Gm + ((size_t)b * TQ + t) * TQ;
  const float cg = cgp[0], cb = cbp[0];
  for (int i = tid; i < t; i += 256) row[i] = R[i];
  __syncthreads();
  float m = -3e38f;
  for (int i = tid; i < t; i += 256) m = fmaxf(m, row[i]);
#pragma unroll
  for (int k = 1; k < 64; k <<= 1) m = fmaxf(m, __shfl_xor(m, k));
  if (lane == 0) r1[wv] = m;
  __syncthreads();
  m = fmaxf(fmaxf(r1[0], r1[1]), fmaxf(r1[2], r1[3]));
  float s = 0.f, sck = 0.f;
  for (int i = tid; i < t; i += 256) {
    const float r = row[i];
    const float e = __expf(r - m);
    const float ck = 1.f / (1.f + __expf(-(r * cg + cb)));
    row[i] = e; s += e; sck += e * ck;
  }
#pragma unroll
  for (int k = 1; k < 64; k <<= 1) { s += __shfl_xor(s, k); sck += __shfl_xor(sck, k); }
  if (lane == 0) { r2[wv] = s; r3[wv] = sck; }
  __syncthreads();
  s = r2[0] + r2[1] + r2[2] + r2[3];
  sck = r3[0] + r3[1] + r3[2] + r3[3];
  const float inv = 1.f / s;
  for (int i = tid; i < t; i += 256) R[i] = row[i] * inv;
  if (tid == 0) Sv[(size_t)b * TQ + t] = sck * inv;
}

// ---------------- K3: persistent recurrence, 8 groups x 32 WGs x 512 thr -----
// Halved fan-in vs R5 (32 publishers/counter, straggler max-of-32, 256 staging
// requestors) at IDENTICAL per-thread register budget: WG owns 64 z-cols and
// 8 kl rows, dc 0..31 x cg 0..15 over 512 threads (wh[16]+wxr[8]+wxl = 25 f4).
// Same split ctrH/ctrA skeleton, wave0-only h publish, de-serialized A-block.
__global__ void __launch_bounds__(NTHR, 2) esbn_scan(
    const float* __restrict__ Wx, const float* __restrict__ Wh,
    const float* __restrict__ bl, const float* __restrict__ Wk,
    const float* __restrict__ bk, const float* __restrict__ Wg,
    const float* __restrict__ bgp, const float* __restrict__ Wmat,
    const float* __restrict__ Sv, float* buf, int* ctrs,
    float* __restrict__ out) {
  __shared__ __align__(16) float st[NBG * STP];      // [h | A] per local batch
  __shared__ __align__(16) float wrow[8 * TQ];       // per-wave softmax row copy
  __shared__ __align__(16) float Mk_s[32 * 520];     // [b*8+kl][tau] key mem
  __shared__ __align__(16) float wkey_s[8 * 520];
  __shared__ __align__(16) float wgv[HQ];
  __shared__ __align__(16) float svl[NBG * TQ];      // Sv rows for this group
  __shared__ __align__(16) float zred[8 * 16 * NBG * 4];
  __shared__ float c_s[NBG * 16];
  __shared__ float bl_s[64];
  __shared__ float bk_s[8];
  __shared__ float bg_s;

  const int tid = threadIdx.x;
  const int wg = blockIdx.x & 31;    // 0..31 within group
  const int grp = blockIdx.x >> 5;   // 0..7
  const int b0 = grp * NBG;
  const int dc = tid >> 4;   // d-chunk 0..31
  const int cg = tid & 15;   // col group (4 cols)

  int colg[4];
#pragma unroll
  for (int j = 0; j < 4; ++j) {
    const int c = cg * 4 + j;                       // 0..63
    colg[j] = (c >> 4) * HQ + wg * 16 + (c & 15);   // gate*H + unit
  }
  f32x4 wh[16], wxr[8], wxl;
#pragma unroll
  for (int i = 0; i < 16; ++i) {
    const int d = (i << 5) + dc;
    wh[i].x = Wh[(size_t)d * G4 + colg[0]];
    wh[i].y = Wh[(size_t)d * G4 + colg[1]];
    wh[i].z = Wh[(size_t)d * G4 + colg[2]];
    wh[i].w = Wh[(size_t)d * G4 + colg[3]];
  }
#pragma unroll
  for (int i = 0; i < 8; ++i) {
    const int d = (i << 5) + dc;
    wxr[i].x = Wx[(size_t)d * G4 + colg[0]];
    wxr[i].y = Wx[(size_t)d * G4 + colg[1]];
    wxr[i].z = Wx[(size_t)d * G4 + colg[2]];
    wxr[i].w = Wx[(size_t)d * G4 + colg[3]];
  }
  wxl.x = wxl.y = wxl.z = wxl.w = 0.f;
  if (dc == 0) {
    wxl.x = Wx[(size_t)256 * G4 + colg[0]];
    wxl.y = Wx[(size_t)256 * G4 + colg[1]];
    wxl.z = Wx[(size_t)256 * G4 + colg[2]];
    wxl.w = Wx[(size_t)256 * G4 + colg[3]];
  }
  for (int i = tid; i < NBG * STP; i += NTHR) st[i] = 0.f;
  for (int i = tid; i < 32 * 520; i += NTHR) Mk_s[i] = 0.f;
  for (int i = tid; i < 8 * 520; i += NTHR) {
    const int kl = i / 520, u = i - kl * 520;
    wkey_s[i] = (u < HQ) ? Wk[(size_t)u * KQ + wg * 8 + kl] : 0.f;
  }
  for (int i = tid; i < HQ; i += NTHR) wgv[i] = Wg[i];
  for (int i = tid; i < NBG * TQ; i += NTHR)
    svl[i] = Sv[(size_t)(b0 + (i >> 9)) * TQ + (i & 511)];
  if (tid < 64) bl_s[tid] = bl[(tid >> 4) * HQ + wg * 16 + (tid & 15)];
  if (tid < 8) bk_s[tid] = bk[wg * 8 + tid];
  if (tid == 0) bg_s = bgp[0];
  if (tid < NBG * 16) c_s[tid] = 0.f;
  __syncthreads();

  int* ctrH = ctrs + grp * 64;       // own 128B line
  int* ctrA = ctrs + grp * 64 + 32;  // own 128B line
  const int wv0 = tid >> 6;          // wave 0..7
  const int yb2 = tid >> 7;          // this wave's batch 0..3
  const int lt = tid & 63;
  const int row = tid >> 4;          // A-block row 0..31 (b = row>>3, kl = row&7)
  const int ytc = tid & 15;

  for (int t = 0; t < TQ; ++t) {
    const int p = t & 1, pn = p ^ 1;
    // prefetch softmax row t into regs (flag-independent; consumed in A-block)
    float wv8[8];
    const bool rowv = (t >= 1) && (t < TQ - 1);
    if (rowv) {
      const float* wr = Wmat + ((size_t)(b0 + yb2) * TQ + t) * TQ + lt;
#pragma unroll
      for (int k = 0; k < 8; ++k) wv8[k] = wr[k << 6];
    }
    if (t > 0) {
      wg_wait_ctr(ctrH, GW * t);   // h_{t-1} published by all 32 WGs
      const float* base = buf + (size_t)(p * BQ + b0) * BROW;
      f32x4 v0;
      const int hb = tid >> 7, off = (tid & 127) << 2;   // 512 f4 chunks
      const float* q0 = base + hb * BROW + off;
      asm volatile("global_load_dwordx4 %0, %1, off sc1" : "=v"(v0) : "v"(q0));
      asm volatile("s_waitcnt vmcnt(0)" : "+v"(v0) : : "memory");
      *(f32x4*)&st[hb * STP + off] = v0;
    }
    __syncthreads();   // st h ready
    // h-part of z (producers' A-block hides under this GEMM)
    f32x4 acc[NBG];
#pragma unroll
    for (int b = 0; b < NBG; ++b) { acc[b].x = acc[b].y = acc[b].z = acc[b].w = 0.f; }
#pragma unroll
    for (int i = 0; i < 16; ++i) {
      const f32x4 w = wh[i];
      const int d = (i << 5) + dc;
#pragma unroll
      for (int b = 0; b < NBG; ++b) acc[b] += st[b * STP + d] * w;
    }
    // g_{t-1}[0..3] per-wave: 16-lane sub-group per batch, broadcast in-wave
    float gv[NBG];
    {
      const int sb = lt >> 4, sl = lt & 15;
      const float* hb = &st[sb * STP];
      float a = 0.f;
#pragma unroll
      for (int j = 0; j < 32; ++j) {
        const int u = sl + (j << 4);
        a += hb[u] * wgv[u];
      }
      a += __shfl_xor(a, 1);
      a += __shfl_xor(a, 2);
      a += __shfl_xor(a, 4);
      a += __shfl_xor(a, 8);
#pragma unroll
      for (int b = 0; b < NBG; ++b) gv[b] = sigm(__shfl(a, b << 4) + bg_s);
    }
    if (t > 0) {
      wg_wait_ctr(ctrA, GW * t);   // A_{t-1} (usually already satisfied)
      if (tid < 256) {             // 256 f4 chunks
        const float* base = buf + (size_t)(p * BQ + b0) * BROW;
        f32x4 v2;
        const int ab = tid >> 6, off2 = (tid & 63) << 2;
        const float* q2 = base + ab * BROW + 512 + off2;
        asm volatile("global_load_dwordx4 %0, %1, off sc1" : "=v"(v2) : "v"(q2));
        asm volatile("s_waitcnt vmcnt(0)" : "+v"(v2) : : "memory");
        *(f32x4*)&st[ab * STP + 512 + off2] = v2;
      }
    }
    __syncthreads();   // st A ready
    // key_r part: pk = A.Wx + S*Wx[256]; z += g*pk
    f32x4 pk[NBG];
#pragma unroll
    for (int b = 0; b < NBG; ++b) { pk[b].x = pk[b].y = pk[b].z = pk[b].w = 0.f; }
#pragma unroll
    for (int i = 0; i < 8; ++i) {
      const f32x4 w = wxr[i];
      const int d = 512 + (i << 5) + dc;
#pragma unroll
      for (int b = 0; b < NBG; ++b) pk[b] += st[b * STP + d] * w;
    }
    if (dc == 0 && t > 0) {
#pragma unroll
      for (int b = 0; b < NBG; ++b) pk[b] += svl[(b << 9) + t - 1] * wxl;
    }
#pragma unroll
    for (int b = 0; b < NBG; ++b) {
      const float g = gv[b];
      acc[b].x += g * pk[b].x; acc[b].y += g * pk[b].y;
      acc[b].z += g * pk[b].z; acc[b].w += g * pk[b].w;
    }
    // reduce over the 4 d-chunks resident in this wave (lane bits 4,5)
#pragma unroll
    for (int m = 16; m <= 32; m <<= 1) {
#pragma unroll
      for (int b = 0; b < NBG; ++b) {
        acc[b].x += __shfl_xor(acc[b].x, m);
        acc[b].y += __shfl_xor(acc[b].y, m);
        acc[b].z += __shfl_xor(acc[b].z, m);
        acc[b].w += __shfl_xor(acc[b].w, m);
      }
    }
    if (lt < 16) {
#pragma unroll
      for (int b = 0; b < NBG; ++b)
        *(f32x4*)&zred[((wv0 * 16 + lt) * NBG + b) * 4] = acc[b];
    }
    __syncthreads();
    if (tid < 64) {   // LSTM pointwise: thread = (b,u), wave 0 only
      const int b = tid >> 4, u = tid & 15;
      float zg[4];
#pragma unroll
      for (int g = 0; g < 4; ++g) {
        const int cgi = g * 4 + (u >> 2), comp = u & 3;
        float z = bl_s[g * 16 + u];
#pragma unroll
        for (int w = 0; w < 8; ++w) z += zred[((w * 16 + cgi) * NBG + b) * 4 + comp];
        zg[g] = z;
      }
      const float gi = sigm(zg[0]);
      const float gf = sigm(zg[1]);
      const float go = sigm(zg[3]);
      const float cn = gf * c_s[tid] + gi * tanhf(zg[2]);
      const float hv = go * tanhf(cn);
      c_s[tid] = cn;
      if (t == TQ - 1) out[(size_t)(b0 + b) * HQ + wg * 16 + u] = hv;
      else st_dev(buf + (size_t)(pn * BQ + b0 + b) * BROW + wg * 16 + u, hv);
    }
    if (t == TQ - 1) break;
    // lean h publish: stores came only from wave 0 -> wave-0 drain + atomic
    if (tid < 64) {
      asm volatile("s_waitcnt vmcnt(0)" ::: "memory");
      if (tid == 0) atomicAdd(ctrH, 1);
    }
    // A-block (off the h critical path): A_t on old Mk, kw folded in at the end.
    // Each wave keeps a private copy of its batch's softmax row (same-wave LDS).
    if (t >= 1) {
      float* wrw = &wrow[wv0 * TQ];
#pragma unroll
      for (int k = 0; k < 8; ++k) wrw[lt + (k << 6)] = wv8[k];
      const int b = row >> 3, kl = row & 7;
      float kw = 0.f, accA = 0.f;
      const float* hrow = &st[b * STP];
      const float* wkr = &wkey_s[kl * 520];
      const float* mk = &Mk_s[row * 520];
#pragma unroll
      for (int j = 0; j < 32; ++j) {
        const int u = ytc + (j << 4);
        kw += hrow[u] * wkr[u];
        accA += wrw[u] * mk[u];   // Mk[t-1] slot still zero: term added below
      }
#pragma unroll
      for (int m = 1; m <= 8; m <<= 1) {
        kw += __shfl_xor(kw, m);
        accA += __shfl_xor(accA, m);
      }
      kw += bk_s[kl];
      accA += wrw[t - 1] * kw;    // the tau = t-1 contribution
      if (ytc == 0) {
        st_dev(buf + (size_t)(pn * BQ + b0 + b) * BROW + 512 + wg * 8 + kl, accA);
        Mk_s[row * 520 + (t - 1)] = kw;
      }
    }
    wg_signal_ctr(ctrA);
  }
}

extern "C" void kernel_launch(void* const* d_in, const int* in_sizes, int n_in,
                              void* d_out, int out_size, void* d_ws, size_t ws_size,
                              hipStream_t stream) {
  (void)in_sizes; (void)n_in; (void)out_size; (void)ws_size;
  const float* X  = (const float*)d_in[0];
  const float* Wx = (const float*)d_in[1];
  const float* Wh = (const float*)d_in[2];
  const float* bl = (const float*)d_in[3];
  const float* Wk = (const float*)d_in[4];
  const float* bk = (const float*)d_in[5];
  const float* Wg = (const float*)d_in[6];
  const float* bg = (const float*)d_in[7];
  const float* cg = (const float*)d_in[8];
  const float* cb = (const float*)d_in[9];
  float* out = (float*)d_out;
  float* ws = (float*)d_ws;

  float* Gm = ws;                              // 32*512*512 = 8,388,608 f
  float* Sv = ws + (size_t)8388608;            // 32*512 = 16,384 f
  float* buf = ws + (size_t)8404992;           // 2*32*768 = 49,152 f
  int* ctrs = (int*)(ws + (size_t)8454144);    // 8 x 64 ints (2 x 128B/group)

  // zero Sv | state double-buffer | counters (one contiguous region)
  hipMemsetAsync(Sv, 0, (size_t)(16384 + 49152 + 512) * 4, stream);
  gram_k<<<dim3(36, BQ), dim3(256), 0, stream>>>(X, Gm);
  smax_k<<<dim3(TQ - 1, BQ), dim3(256), 0, stream>>>(Gm, Sv, cg, cb);

  void* args[] = {(void*)&Wx, (void*)&Wh, (void*)&bl, (void*)&Wk, (void*)&bk,
                  (void*)&Wg, (void*)&bg, (void*)&Gm, (void*)&Sv,
                  (void*)&buf, (void*)&ctrs, (void*)&out};
  hipError_t e = hipLaunchCooperativeKernel((const void*)esbn_scan, dim3(NWG),
                                            dim3(NTHR), args, 0, stream);
  if (e != hipSuccess) {
    esbn_scan<<<dim3(NWG), dim3(NTHR), 0, stream>>>(Wx, Wh, bl, Wk, bk, Wg, bg,
                                                    Gm, Sv, buf, ctrs, out);
  }
}